// Round 1
// baseline (497.555 us; speedup 1.0000x reference)
//
#include <hip/hip_runtime.h>

#define BB 8
#define CC 64
#define NN 4096
#define LOG2E 1.4426950408889634f

typedef float f32x4 __attribute__((ext_vector_type(4)));
typedef _Float16 half8_t __attribute__((ext_vector_type(8)));
typedef _Float16 half4_t __attribute__((ext_vector_type(4)));

// ---------------------------------------------------------------------------
// Kernel A: 1x1-conv QKV. grid (NN/64, B, 3), block 64 (1 wave).
// z=0 -> fT[b][n][c] (scaled by log2e, f16), z=1 -> gT[b][n][c], z=2 -> h[b][c][n]
// ---------------------------------------------------------------------------
__global__ __launch_bounds__(64) void qkv_kernel(
    const float* __restrict__ x,
    const float* __restrict__ Wf, const float* __restrict__ bf,
    const float* __restrict__ Wg, const float* __restrict__ bg,
    const float* __restrict__ Wh, const float* __restrict__ bh,
    _Float16* __restrict__ fT, _Float16* __restrict__ gT,
    _Float16* __restrict__ hM)
{
    const int n = blockIdx.x * 64 + threadIdx.x;
    const int b = blockIdx.y;
    const int z = blockIdx.z;
    const float* W    = (z == 0) ? Wf : ((z == 1) ? Wg : Wh);
    const float* bias = (z == 0) ? bf : ((z == 1) ? bg : bh);

    float xv[CC];
    const float* xp = x + (size_t)b * CC * NN + n;
#pragma unroll
    for (int c = 0; c < CC; ++c) xv[c] = xp[(size_t)c * NN];

    if (z < 2) {
        _Float16* dst = ((z == 0) ? fT : gT) + (size_t)(b * NN + n) * CC;
        const float scale = (z == 0) ? LOG2E : 1.0f;
        for (int o8 = 0; o8 < 8; ++o8) {
            half8_t v;
#pragma unroll
            for (int oo = 0; oo < 8; ++oo) {
                const int o = o8 * 8 + oo;
                float acc = bias[o];
#pragma unroll
                for (int c = 0; c < CC; ++c) acc += W[o * CC + c] * xv[c];
                v[oo] = (_Float16)(acc * scale);
            }
            *(half8_t*)(dst + o8 * 8) = v;
        }
    } else {
        for (int o = 0; o < CC; ++o) {
            float acc = bias[o];
#pragma unroll
            for (int c = 0; c < CC; ++c) acc += W[o * CC + c] * xv[c];
            hM[(size_t)(b * CC + o) * NN + n] = (_Float16)acc;
        }
    }
}

// ---------------------------------------------------------------------------
// Kernel B: row stats. grid (NN/64, B), block 256 (4 waves, 16 rows each).
// t = S*log2e comes straight out of MFMA (f pre-scaled). Online base-2 softmax.
// ---------------------------------------------------------------------------
__global__ __launch_bounds__(256) void stats_kernel(
    const _Float16* __restrict__ fT, const _Float16* __restrict__ gT,
    float* __restrict__ mrow, float* __restrict__ rrow)
{
    const int lane = threadIdx.x & 63;
    const int wv   = threadIdx.x >> 6;
    const int b    = blockIdx.y;
    const int i0   = blockIdx.x * 64 + wv * 16;
    const int lm   = lane & 15;
    const int quad = lane >> 4;

    // A-frags for this wave's 16 rows (fixed across the whole j-stream)
    const _Float16* fa = fT + (size_t)(b * NN + i0 + lm) * CC + quad * 8;
    const half8_t a0 = *(const half8_t*)(fa);
    const half8_t a1 = *(const half8_t*)(fa + 32);

    float m[4] = {-3e38f, -3e38f, -3e38f, -3e38f};
    float l[4] = {0.f, 0.f, 0.f, 0.f};

    const _Float16* gp = gT + (size_t)(b * NN + lm) * CC + quad * 8;
    for (int jt = 0; jt < NN / 16; ++jt) {
        const half8_t b0 = *(const half8_t*)(gp);
        const half8_t b1 = *(const half8_t*)(gp + 32);
        gp += 16 * CC;
        f32x4 acc = {0.f, 0.f, 0.f, 0.f};
        acc = __builtin_amdgcn_mfma_f32_16x16x32_f16(a0, b0, acc, 0, 0, 0);
        acc = __builtin_amdgcn_mfma_f32_16x16x32_f16(a1, b1, acc, 0, 0, 0);
#pragma unroll
        for (int r = 0; r < 4; ++r) {
            const float v  = acc[r];
            const float mn = fmaxf(m[r], v);
            l[r] = l[r] * __builtin_exp2f(m[r] - mn) + __builtin_exp2f(v - mn);
            m[r] = mn;
        }
    }

    // reduce across the 16 lanes (same rows, different j) of each quad-group
#pragma unroll
    for (int r = 0; r < 4; ++r) {
#pragma unroll
        for (int off = 1; off < 16; off <<= 1) {
            const float om = __shfl_xor(m[r], off);
            const float ol = __shfl_xor(l[r], off);
            const float mn = fmaxf(m[r], om);
            l[r] = l[r] * __builtin_exp2f(m[r] - mn) + ol * __builtin_exp2f(om - mn);
            m[r] = mn;
        }
    }

    if (lm == 0) {
        const int ib = b * NN + i0 + quad * 4;
#pragma unroll
        for (int r = 0; r < 4; ++r) {
            mrow[ib + r] = m[r];
            rrow[ib + r] = 1.0f / l[r];
        }
    }
}

// ---------------------------------------------------------------------------
// Kernel C: out = gamma * (h @ P) + x. grid (NN/64, B), block 256.
// Each wave owns 16 output columns j; streams i in tiles of 32.
// ---------------------------------------------------------------------------
__global__ __launch_bounds__(256) void attn_kernel(
    const float* __restrict__ x, const float* __restrict__ gammap,
    const _Float16* __restrict__ fT, const _Float16* __restrict__ gT,
    const _Float16* __restrict__ hM,
    const float* __restrict__ mrow, const float* __restrict__ rrow,
    float* __restrict__ out)
{
    __shared__ _Float16 Pbuf[4][16][40];  // [wave][j][i-tile of 32, pad->40]

    const int lane = threadIdx.x & 63;
    const int wv   = threadIdx.x >> 6;
    const int b    = blockIdx.y;
    const int lm   = lane & 15;
    const int quad = lane >> 4;
    const int jw   = blockIdx.x * 64 + wv * 16;
    const int j    = jw + lm;

    const float gam = gammap[0];

    // g B-frags fixed per wave (16 j's, K=64)
    const _Float16* gp = gT + (size_t)(b * NN + j) * CC + quad * 8;
    const half8_t bg0 = *(const half8_t*)(gp);
    const half8_t bg1 = *(const half8_t*)(gp + 32);

    f32x4 acc[4];
#pragma unroll
    for (int ct = 0; ct < 4; ++ct) acc[ct] = (f32x4){0.f, 0.f, 0.f, 0.f};

    const _Float16* fbase = fT + (size_t)b * NN * CC;
    const _Float16* hbase = hM + (size_t)b * CC * NN;
    const float*    mb    = mrow + b * NN;
    const float*    rb    = rrow + b * NN;

    for (int it = 0; it < NN / 32; ++it) {
        const int i0 = it * 32;
#pragma unroll
        for (int ih = 0; ih < 2; ++ih) {
            const _Float16* fa = fbase + (size_t)(i0 + ih * 16 + lm) * CC + quad * 8;
            const half8_t a0 = *(const half8_t*)(fa);
            const half8_t a1 = *(const half8_t*)(fa + 32);
            f32x4 s = {0.f, 0.f, 0.f, 0.f};
            s = __builtin_amdgcn_mfma_f32_16x16x32_f16(a0, bg0, s, 0, 0, 0);
            s = __builtin_amdgcn_mfma_f32_16x16x32_f16(a1, bg1, s, 0, 0, 0);
            const f32x4 m4 = *(const f32x4*)(mb + i0 + ih * 16 + quad * 4);
            const f32x4 r4 = *(const f32x4*)(rb + i0 + ih * 16 + quad * 4);
            half4_t pv;
#pragma unroll
            for (int r = 0; r < 4; ++r)
                pv[r] = (_Float16)(__builtin_exp2f(s[r] - m4[r]) * r4[r]);
            *(half4_t*)&Pbuf[wv][lm][ih * 16 + quad * 4] = pv;
        }
        __syncthreads();
        const half8_t pb = *(const half8_t*)&Pbuf[wv][lm][quad * 8];
#pragma unroll
        for (int ct = 0; ct < 4; ++ct) {
            const _Float16* ha = hbase + (size_t)(ct * 16 + lm) * NN + i0 + quad * 8;
            const half8_t ah = *(const half8_t*)(ha);
            acc[ct] = __builtin_amdgcn_mfma_f32_16x16x32_f16(ah, pb, acc[ct], 0, 0, 0);
        }
        __syncthreads();
    }

    // epilogue: out = gamma * acc + x   (D layout: col=lm -> j, row=quad*4+r -> c)
#pragma unroll
    for (int ct = 0; ct < 4; ++ct) {
#pragma unroll
        for (int r = 0; r < 4; ++r) {
            const int c = ct * 16 + quad * 4 + r;
            const size_t idx = (size_t)(b * CC + c) * NN + j;
            out[idx] = gam * acc[ct][r] + x[idx];
        }
    }
}

// ---------------------------------------------------------------------------
extern "C" void kernel_launch(void* const* d_in, const int* in_sizes, int n_in,
                              void* d_out, int out_size, void* d_ws, size_t ws_size,
                              hipStream_t stream) {
    const float* x     = (const float*)d_in[0];
    const float* Wf    = (const float*)d_in[1];
    const float* bf    = (const float*)d_in[2];
    const float* Wg    = (const float*)d_in[3];
    const float* bg    = (const float*)d_in[4];
    const float* Wh    = (const float*)d_in[5];
    const float* bh    = (const float*)d_in[6];
    const float* gamma = (const float*)d_in[7];
    float* out = (float*)d_out;

    _Float16* fT = (_Float16*)d_ws;
    _Float16* gT = fT + (size_t)BB * NN * CC;
    _Float16* hM = gT + (size_t)BB * NN * CC;
    float* mrow  = (float*)(hM + (size_t)BB * NN * CC);
    float* rrow  = mrow + BB * NN;

    qkv_kernel<<<dim3(NN / 64, BB, 3), 64, 0, stream>>>(
        x, Wf, bf, Wg, bg, Wh, bh, fT, gT, hM);
    stats_kernel<<<dim3(NN / 64, BB), 256, 0, stream>>>(fT, gT, mrow, rrow);
    attn_kernel<<<dim3(NN / 64, BB), 256, 0, stream>>>(
        x, gamma, fT, gT, hM, mrow, rrow, out);
}